// Round 1
// baseline (130.332 us; speedup 1.0000x reference)
//
#include <hip/hip_runtime.h>

// Problem constants (match reference):
//   B = 8192 batches, N = 64 antennas, K = 16 users, NOISE = 1.0
//   H: [B, N, K, 2] f32  (re/im interleaved, stride 32 floats per n-row)
//   P: [B, 2*N*K]  f32  (first N*K = Pr[n][j], second N*K = Pi[n][j])
// Output: scalar f32 = -(1/B) * sum_{b,k} log2(1 + sig/interf)

__global__ void zero_out_kernel(float* __restrict__ out) {
    out[0] = 0.0f;
}

__global__ __launch_bounds__(256) void sumrate_kernel(
        const float* __restrict__ H, const float* __restrict__ P,
        float* __restrict__ out) {
    const int wave = threadIdx.x >> 6;       // 4 waves per block, 1 batch each
    const int lane = threadIdx.x & 63;
    const int b    = blockIdx.x * 4 + wave;
    const int a    = lane >> 3;              // k-pair index 0..7  (k0 = 2a)
    const int c    = lane & 7;               // j-pair index 0..7  (j0 = 2c)

    const float* Hb  = H + (size_t)b * 2048 + 4 * a;      // H[b][n][2a..2a+1][re,im]
    const float* PbR = P + (size_t)b * 2048 + 2 * c;      // Pr[b][n][2c..2c+1]
    const float* PbI = PbR + 1024;                        // Pi[b][n][2c..2c+1]

    // 2x2 complex accumulator tile: rows k0,k1 x cols j0,j1
    float re00 = 0.f, im00 = 0.f, re01 = 0.f, im01 = 0.f;
    float re10 = 0.f, im10 = 0.f, re11 = 0.f, im11 = 0.f;

    #pragma unroll 8
    for (int n = 0; n < 64; ++n) {
        const float4 h  = *reinterpret_cast<const float4*>(Hb  + n * 32);
        const float2 pr = *reinterpret_cast<const float2*>(PbR + n * 16);
        const float2 pi = *reinterpret_cast<const float2*>(PbI + n * 16);
        // h.x = H[n][k0].re, h.y = H[n][k0].im, h.z = H[n][k1].re, h.w = H[n][k1].im
        // (hre + i*him)*(pr + i*pi): re += hre*pr - him*pi; im += hre*pi + him*pr
        re00 = fmaf(h.x, pr.x, re00); re00 = fmaf(-h.y, pi.x, re00);
        im00 = fmaf(h.x, pi.x, im00); im00 = fmaf( h.y, pr.x, im00);
        re01 = fmaf(h.x, pr.y, re01); re01 = fmaf(-h.y, pi.y, re01);
        im01 = fmaf(h.x, pi.y, im01); im01 = fmaf( h.y, pr.y, im01);
        re10 = fmaf(h.z, pr.x, re10); re10 = fmaf(-h.w, pi.x, re10);
        im10 = fmaf(h.z, pi.x, im10); im10 = fmaf( h.w, pr.x, im10);
        re11 = fmaf(h.z, pr.y, re11); re11 = fmaf(-h.w, pi.y, re11);
        im11 = fmaf(h.z, pi.y, im11); im11 = fmaf( h.w, pr.y, im11);
    }

    const float m00 = re00 * re00 + im00 * im00;
    const float m01 = re01 * re01 + im01 * im01;
    const float m10 = re10 * re10 + im10 * im10;
    const float m11 = re11 * re11 + im11 * im11;

    // Row totals over this lane's 2 j's; diagonal hits only where c == a
    // (j0==k0 <=> 2c==2a; j1==k1 <=> 2c+1==2a+1; odd/even cross terms impossible).
    float tot0 = m00 + m01;
    float tot1 = m10 + m11;
    float sig0 = (c == a) ? m00 : 0.0f;
    float sig1 = (c == a) ? m11 : 0.0f;

    // Reduce across the c dimension (low 3 lane bits): every lane in the
    // 8-lane group ends with full row-sum and the diagonal value.
    #pragma unroll
    for (int m = 1; m < 8; m <<= 1) {
        tot0 += __shfl_xor(tot0, m, 64);
        tot1 += __shfl_xor(tot1, m, 64);
        sig0 += __shfl_xor(sig0, m, 64);
        sig1 += __shfl_xor(sig1, m, 64);
    }

    // interf = total - sig + NOISE (NOISE = 1.0)
    float rate = log2f(1.0f + sig0 / (tot0 - sig0 + 1.0f))
               + log2f(1.0f + sig1 / (tot1 - sig1 + 1.0f));

    // Reduce across the a dimension (lane bits 3..5). Lanes within a c-group
    // hold identical values, so each of the 8 group-values is summed once.
    #pragma unroll
    for (int m = 8; m < 64; m <<= 1) {
        rate += __shfl_xor(rate, m, 64);
    }

    if (lane == 0) {
        atomicAdd(out, rate * (-1.0f / 8192.0f));
    }
}

extern "C" void kernel_launch(void* const* d_in, const int* in_sizes, int n_in,
                              void* d_out, int out_size, void* d_ws, size_t ws_size,
                              hipStream_t stream) {
    const float* H = (const float*)d_in[0];
    const float* P = (const float*)d_in[1];
    float* out = (float*)d_out;

    zero_out_kernel<<<1, 1, 0, stream>>>(out);
    // 8192 batches, 1 wave (64 lanes) per batch, 4 batches per 256-thread block
    sumrate_kernel<<<8192 / 4, 256, 0, stream>>>(H, P, out);
}

// Round 2
// 123.681 us; speedup vs baseline: 1.0538x; 1.0538x over previous
//
#include <hip/hip_runtime.h>

// Problem constants (match reference):
//   B = 8192 batches, N = 64 antennas, K = 16 users, NOISE = 1.0
//   H: [B, N, K, 2] f32  (re/im interleaved, 32 floats per n-row)
//   P: [B, 2*N*K]  f32  (first N*K = Pr[n][j], second N*K = Pi[n][j])
// Output: scalar f32 = -(1/B) * sum_{b,k} log2(1 + sig/interf)
//
// Strategy: one wave per batch. Stage the batch's 16 KB (H 8KB + P 8KB)
// into a per-wave LDS region with 16 coalesced global_load_lds (width=16,
// 1 KB per instruction) -> huge MLP, 12x fewer VMEM instructions. Then the
// dup-8 fragment reads hit LDS where same-address broadcast is free.

__global__ void zero_out_kernel(float* __restrict__ out) {
    out[0] = 0.0f;
}

__device__ __forceinline__ void gload16(const float* g, float* s) {
    __builtin_amdgcn_global_load_lds(
        (const __attribute__((address_space(1))) void*)g,
        (__attribute__((address_space(3))) void*)s,
        16, 0, 0);
}

__global__ __launch_bounds__(128) void sumrate_kernel(
        const float* __restrict__ H, const float* __restrict__ P,
        float* __restrict__ out) {
    __shared__ float sData[2 * 4096];        // 2 waves x 16KB = 32KB/block

    const int wave = threadIdx.x >> 6;       // 2 waves per block, 1 batch each
    const int lane = threadIdx.x & 63;
    const int b    = blockIdx.x * 2 + wave;
    const int a    = lane >> 3;              // k-pair index 0..7  (k0 = 2a)
    const int c    = lane & 7;               // j-pair index 0..7  (j0 = 2c)

    float* sW = sData + wave * 4096;         // this wave's 16KB region
    const float* gH = H + (size_t)b * 2048;  // 8KB: [n][k][re,im]
    const float* gP = P + (size_t)b * 2048;  // 8KB: pr[1024] then pi[1024]

    // ---- Stage batch into LDS: 16 x 1KB coalesced direct-to-LDS loads ----
    // LDS dest is wave-uniform base + lane*16; global src is per-lane.
    #pragma unroll
    for (int i = 0; i < 8; ++i)
        gload16(gH + i * 256 + lane * 4, sW + i * 256);
    #pragma unroll
    for (int i = 0; i < 8; ++i)
        gload16(gP + i * 256 + lane * 4, sW + 2048 + i * 256);

    asm volatile("s_waitcnt vmcnt(0)" ::: "memory");
    __builtin_amdgcn_sched_barrier(0);
    // Same-wave produce->consume: no s_barrier needed.

    const float* sHa = sW + 4 * a;               // H[n][2a..2a+1][re,im]
    const float* sPr = sW + 2048 + 2 * c;        // Pr[n][2c..2c+1]
    const float* sPi = sPr + 1024;               // Pi[n][2c..2c+1]

    // 2x2 complex accumulator tile: rows k0,k1 x cols j0,j1
    float re00 = 0.f, im00 = 0.f, re01 = 0.f, im01 = 0.f;
    float re10 = 0.f, im10 = 0.f, re11 = 0.f, im11 = 0.f;

    #pragma unroll 8
    for (int n = 0; n < 64; ++n) {
        const float4 h  = *reinterpret_cast<const float4*>(sHa + n * 32);
        const float2 pr = *reinterpret_cast<const float2*>(sPr + n * 16);
        const float2 pi = *reinterpret_cast<const float2*>(sPi + n * 16);
        // h.x=H[n][k0].re h.y=H[n][k0].im h.z=H[n][k1].re h.w=H[n][k1].im
        re00 = fmaf(h.x, pr.x, re00); re00 = fmaf(-h.y, pi.x, re00);
        im00 = fmaf(h.x, pi.x, im00); im00 = fmaf( h.y, pr.x, im00);
        re01 = fmaf(h.x, pr.y, re01); re01 = fmaf(-h.y, pi.y, re01);
        im01 = fmaf(h.x, pi.y, im01); im01 = fmaf( h.y, pr.y, im01);
        re10 = fmaf(h.z, pr.x, re10); re10 = fmaf(-h.w, pi.x, re10);
        im10 = fmaf(h.z, pi.x, im10); im10 = fmaf( h.w, pr.x, im10);
        re11 = fmaf(h.z, pr.y, re11); re11 = fmaf(-h.w, pi.y, re11);
        im11 = fmaf(h.z, pi.y, im11); im11 = fmaf( h.w, pr.y, im11);
    }

    const float m00 = re00 * re00 + im00 * im00;
    const float m01 = re01 * re01 + im01 * im01;
    const float m10 = re10 * re10 + im10 * im10;
    const float m11 = re11 * re11 + im11 * im11;

    // Row totals over this lane's 2 j's; diagonal hits only where c == a.
    float tot0 = m00 + m01;
    float tot1 = m10 + m11;
    float sig0 = (c == a) ? m00 : 0.0f;
    float sig1 = (c == a) ? m11 : 0.0f;

    // Reduce across the c dimension (low 3 lane bits).
    #pragma unroll
    for (int m = 1; m < 8; m <<= 1) {
        tot0 += __shfl_xor(tot0, m, 64);
        tot1 += __shfl_xor(tot1, m, 64);
        sig0 += __shfl_xor(sig0, m, 64);
        sig1 += __shfl_xor(sig1, m, 64);
    }

    // interf = total - sig + NOISE (NOISE = 1.0)
    float rate = log2f(1.0f + sig0 / (tot0 - sig0 + 1.0f))
               + log2f(1.0f + sig1 / (tot1 - sig1 + 1.0f));

    // Reduce across the a dimension (lane bits 3..5).
    #pragma unroll
    for (int m = 8; m < 64; m <<= 1) {
        rate += __shfl_xor(rate, m, 64);
    }

    if (lane == 0) {
        atomicAdd(out, rate * (-1.0f / 8192.0f));
    }
}

extern "C" void kernel_launch(void* const* d_in, const int* in_sizes, int n_in,
                              void* d_out, int out_size, void* d_ws, size_t ws_size,
                              hipStream_t stream) {
    const float* H = (const float*)d_in[0];
    const float* P = (const float*)d_in[1];
    float* out = (float*)d_out;

    zero_out_kernel<<<1, 1, 0, stream>>>(out);
    // 8192 batches, 1 wave per batch, 2 waves (batches) per 128-thread block
    sumrate_kernel<<<8192 / 2, 128, 0, stream>>>(H, P, out);
}

// Round 3
// 36.521 us; speedup vs baseline: 3.5687x; 3.3866x over previous
//
#include <hip/hip_runtime.h>

// Problem constants (match reference):
//   B = 8192 batches, N = 64 antennas, K = 16 users, NOISE = 1.0
//   H: [B, N, K, 2] f32  (re/im interleaved, 32 floats per n-row)
//   P: [B, 2*N*K]  f32  (first N*K = Pr[n][j], second N*K = Pi[n][j])
// Output: scalar f32 = -(1/B) * sum_{b,k} log2(1 + sig/interf)
//
// R3: R0/R1/R2 all plateaued at ~125us because all 8192 waves atomicAdd'ed
// the SAME address (same-line atomic RMW serializes in one L2 slice at
// ~35cyc each = ~120us). This round: per-wave plain store to d_ws[b],
// then a one-block reduction kernel writes out[0]. Zero atomics.

__device__ __forceinline__ void gload16(const float* g, float* s) {
    __builtin_amdgcn_global_load_lds(
        (const __attribute__((address_space(1))) void*)g,
        (__attribute__((address_space(3))) void*)s,
        16, 0, 0);
}

__global__ __launch_bounds__(128) void sumrate_kernel(
        const float* __restrict__ H, const float* __restrict__ P,
        float* __restrict__ ws) {
    __shared__ float sData[2 * 4096];        // 2 waves x 16KB = 32KB/block

    const int wave = threadIdx.x >> 6;       // 2 waves per block, 1 batch each
    const int lane = threadIdx.x & 63;
    const int b    = blockIdx.x * 2 + wave;
    const int a    = lane >> 3;              // k-pair index 0..7  (k0 = 2a)
    const int c    = lane & 7;               // j-pair index 0..7  (j0 = 2c)

    float* sW = sData + wave * 4096;         // this wave's 16KB region
    const float* gH = H + (size_t)b * 2048;  // 8KB: [n][k][re,im]
    const float* gP = P + (size_t)b * 2048;  // 8KB: pr[1024] then pi[1024]

    // ---- Stage batch into LDS: 16 x 1KB coalesced direct-to-LDS loads ----
    #pragma unroll
    for (int i = 0; i < 8; ++i)
        gload16(gH + i * 256 + lane * 4, sW + i * 256);
    #pragma unroll
    for (int i = 0; i < 8; ++i)
        gload16(gP + i * 256 + lane * 4, sW + 2048 + i * 256);

    asm volatile("s_waitcnt vmcnt(0)" ::: "memory");
    __builtin_amdgcn_sched_barrier(0);
    // Same-wave produce->consume: no s_barrier needed.

    const float* sHa = sW + 4 * a;               // H[n][2a..2a+1][re,im]
    const float* sPr = sW + 2048 + 2 * c;        // Pr[n][2c..2c+1]
    const float* sPi = sPr + 1024;               // Pi[n][2c..2c+1]

    // 2x2 complex accumulator tile: rows k0,k1 x cols j0,j1
    float re00 = 0.f, im00 = 0.f, re01 = 0.f, im01 = 0.f;
    float re10 = 0.f, im10 = 0.f, re11 = 0.f, im11 = 0.f;

    #pragma unroll 8
    for (int n = 0; n < 64; ++n) {
        const float4 h  = *reinterpret_cast<const float4*>(sHa + n * 32);
        const float2 pr = *reinterpret_cast<const float2*>(sPr + n * 16);
        const float2 pi = *reinterpret_cast<const float2*>(sPi + n * 16);
        re00 = fmaf(h.x, pr.x, re00); re00 = fmaf(-h.y, pi.x, re00);
        im00 = fmaf(h.x, pi.x, im00); im00 = fmaf( h.y, pr.x, im00);
        re01 = fmaf(h.x, pr.y, re01); re01 = fmaf(-h.y, pi.y, re01);
        im01 = fmaf(h.x, pi.y, im01); im01 = fmaf( h.y, pr.y, im01);
        re10 = fmaf(h.z, pr.x, re10); re10 = fmaf(-h.w, pi.x, re10);
        im10 = fmaf(h.z, pi.x, im10); im10 = fmaf( h.w, pr.x, im10);
        re11 = fmaf(h.z, pr.y, re11); re11 = fmaf(-h.w, pi.y, re11);
        im11 = fmaf(h.z, pi.y, im11); im11 = fmaf( h.w, pr.y, im11);
    }

    const float m00 = re00 * re00 + im00 * im00;
    const float m01 = re01 * re01 + im01 * im01;
    const float m10 = re10 * re10 + im10 * im10;
    const float m11 = re11 * re11 + im11 * im11;

    // Row totals over this lane's 2 j's; diagonal hits only where c == a.
    float tot0 = m00 + m01;
    float tot1 = m10 + m11;
    float sig0 = (c == a) ? m00 : 0.0f;
    float sig1 = (c == a) ? m11 : 0.0f;

    // Reduce across the c dimension (low 3 lane bits).
    #pragma unroll
    for (int m = 1; m < 8; m <<= 1) {
        tot0 += __shfl_xor(tot0, m, 64);
        tot1 += __shfl_xor(tot1, m, 64);
        sig0 += __shfl_xor(sig0, m, 64);
        sig1 += __shfl_xor(sig1, m, 64);
    }

    // interf = total - sig + NOISE (NOISE = 1.0)
    float rate = log2f(1.0f + sig0 / (tot0 - sig0 + 1.0f))
               + log2f(1.0f + sig1 / (tot1 - sig1 + 1.0f));

    // Reduce across the a dimension (lane bits 3..5).
    #pragma unroll
    for (int m = 8; m < 64; m <<= 1) {
        rate += __shfl_xor(rate, m, 64);
    }

    if (lane == 0) {
        ws[b] = rate;   // plain store, no contention
    }
}

// One block reduces the 8192 per-batch rates and writes the scalar loss.
__global__ __launch_bounds__(1024) void reduce_kernel(
        const float* __restrict__ ws, float* __restrict__ out) {
    __shared__ float sPart[16];
    float s = 0.0f;
    #pragma unroll
    for (int i = 0; i < 8; ++i)
        s += ws[threadIdx.x + i * 1024];

    #pragma unroll
    for (int m = 1; m < 64; m <<= 1)
        s += __shfl_xor(s, m, 64);

    const int w = threadIdx.x >> 6;
    const int l = threadIdx.x & 63;
    if (l == 0) sPart[w] = s;
    __syncthreads();

    if (w == 0) {
        float t = (l < 16) ? sPart[l] : 0.0f;
        #pragma unroll
        for (int m = 1; m < 16; m <<= 1)
            t += __shfl_xor(t, m, 64);
        if (l == 0) out[0] = t * (-1.0f / 8192.0f);
    }
}

extern "C" void kernel_launch(void* const* d_in, const int* in_sizes, int n_in,
                              void* d_out, int out_size, void* d_ws, size_t ws_size,
                              hipStream_t stream) {
    const float* H = (const float*)d_in[0];
    const float* P = (const float*)d_in[1];
    float* out = (float*)d_out;
    float* ws  = (float*)d_ws;   // 8192 floats of per-batch rates

    // 8192 batches, 1 wave per batch, 2 waves (batches) per 128-thread block
    sumrate_kernel<<<8192 / 2, 128, 0, stream>>>(H, P, ws);
    reduce_kernel<<<1, 1024, 0, stream>>>(ws, out);
}

// Round 5
// 27.304 us; speedup vs baseline: 4.7734x; 1.3376x over previous
//
#include <hip/hip_runtime.h>

// Problem constants (match reference):
//   B = 8192 batches, N = 64 antennas, K = 16 users, NOISE = 1.0
//   H: [B, N, K, 2] f32  (re/im interleaved, 32 floats per n-row)
//   P: [B, 2*N*K]  f32  (first N*K = Pr[n][j], second N*K = Pi[n][j])
// Output: scalar f32 = -(1/B) * sum_{b,k} log2(1 + sig/interf)
//
// R5 (= R4 with compile fix): complex 16x16x64 matmul per batch via
// 8 x mfma_f32_16x16x32_bf16. One wave per batch; each lane global-loads
// its A/B fragments directly (every byte exactly once, coalesced),
// converts f32->bf16 in-register via v_cvt_pk_bf16_f32 (inline asm — no
// builtin exists on gfx950 and __hip_bfloat162 can't be bit_cast).
// No LDS, no atomics. A/B share the same (lane,reg)->n map so the
// n-permutation inside the instruction cancels; C/D layout:
// col=lane&15, row=4*(lane>>4)+reg (m89-verified).

typedef short bf16x8 __attribute__((ext_vector_type(8)));
typedef float f32x4  __attribute__((ext_vector_type(4)));
typedef int   i32x4  __attribute__((ext_vector_type(4)));

__device__ __forceinline__ int pk2(float lo, float hi) {
    int r;
    asm("v_cvt_pk_bf16_f32 %0, %1, %2" : "=v"(r) : "v"(lo), "v"(hi));
    return r;   // bf16(lo) in low 16 bits, bf16(hi) in high 16 bits (RNE)
}

__device__ __forceinline__ bf16x8 mk8(const float* v) {  // v[8] -> packed bf16 frag
    i32x4 t;
    #pragma unroll
    for (int i = 0; i < 4; ++i) t[i] = pk2(v[2 * i], v[2 * i + 1]);
    return __builtin_bit_cast(bf16x8, t);
}

__device__ __forceinline__ bf16x8 negbf(bf16x8 a) {      // flip all 8 sign bits
    i32x4 t = __builtin_bit_cast(i32x4, a);
    #pragma unroll
    for (int i = 0; i < 4; ++i) t[i] ^= 0x80008000;
    return __builtin_bit_cast(bf16x8, t);
}

#define MFMA __builtin_amdgcn_mfma_f32_16x16x32_bf16

__global__ __launch_bounds__(256) void sumrate_kernel(
        const float* __restrict__ H, const float* __restrict__ P,
        float* __restrict__ ws) {
    const int wave = threadIdx.x >> 6;        // 4 waves/block, 1 batch each
    const int lane = threadIdx.x & 63;
    const int b    = blockIdx.x * 4 + wave;
    const int j    = lane & 15;               // A row (k) and B col (j)
    const int g    = lane >> 4;               // n-slice group 0..3
    const int n0   = g * 8;                   // this lane's base n

    const float* Hb = H + (size_t)b * 2048;
    const float* Pb = P + (size_t)b * 2048;
    const float* hA = Hb + n0 * 32 + 2 * j;   // (re,im) of H[n][k], n-stride 32 f
    const float* pB = Pb + n0 * 16 + j;       // Pr[n][j], n-stride 16 f

    // ---- Global loads: every byte exactly once, coalesced ----
    float ar0[8], ai0[8], ar1[8], ai1[8];     // H halves (n 0..31 / 32..63)
    float pr0[8], pr1[8], pi0[8], pi1[8];     // P halves, re/im
    #pragma unroll
    for (int r = 0; r < 8; ++r) {
        const float2 h0 = *reinterpret_cast<const float2*>(hA + r * 32);
        const float2 h1 = *reinterpret_cast<const float2*>(hA + 1024 + r * 32);
        ar0[r] = h0.x; ai0[r] = h0.y;
        ar1[r] = h1.x; ai1[r] = h1.y;
        pr0[r] = pB[r * 16];
        pr1[r] = pB[512 + r * 16];
        pi0[r] = pB[1024 + r * 16];
        pi1[r] = pB[1536 + r * 16];
    }

    // ---- Pack bf16 fragments (A and B use the identical (lane,reg)->n map) ----
    const bf16x8 Ahr0 = mk8(ar0), Ahr1 = mk8(ar1);
    const bf16x8 Ahi0 = mk8(ai0), Ahi1 = mk8(ai1);
    const bf16x8 Bpr0 = mk8(pr0), Bpr1 = mk8(pr1);
    const bf16x8 Bpi0 = mk8(pi0), Bpi1 = mk8(pi1);

    // ---- Complex 16x16x64 matmul: Dr = HrPr - HiPi, Di = HrPi + HiPr ----
    f32x4 dr = {0.f, 0.f, 0.f, 0.f}, di = {0.f, 0.f, 0.f, 0.f};
    dr = MFMA(Ahr0, Bpr0, dr, 0, 0, 0);
    dr = MFMA(Ahr1, Bpr1, dr, 0, 0, 0);
    dr = MFMA(negbf(Ahi0), Bpi0, dr, 0, 0, 0);
    dr = MFMA(negbf(Ahi1), Bpi1, dr, 0, 0, 0);
    di = MFMA(Ahr0, Bpi0, di, 0, 0, 0);
    di = MFMA(Ahr1, Bpi1, di, 0, 0, 0);
    di = MFMA(Ahi0, Bpr0, di, 0, 0, 0);
    di = MFMA(Ahi1, Bpr1, di, 0, 0, 0);

    // ---- Epilogue: C/D layout col=j=lane&15, row=k=4*g+reg ----
    float tot[4], sig[4];
    #pragma unroll
    for (int r = 0; r < 4; ++r) {
        const float mag = dr[r] * dr[r] + di[r] * di[r];
        const int k = g * 4 + r;
        tot[r] = mag;
        sig[r] = (j == k) ? mag : 0.0f;
    }
    // Row-sum over j: reduce across the 16 lanes of this g-group (low 4 bits).
    #pragma unroll
    for (int m = 1; m < 16; m <<= 1) {
        #pragma unroll
        for (int r = 0; r < 4; ++r) {
            tot[r] += __shfl_xor(tot[r], m, 64);
            sig[r] += __shfl_xor(sig[r], m, 64);
        }
    }
    // rate for this group's 4 k's (identical across the 16 lanes of the group)
    float rate = 0.0f;
    #pragma unroll
    for (int r = 0; r < 4; ++r)
        rate += log2f(1.0f + sig[r] / (tot[r] - sig[r] + 1.0f));
    // Sum the 4 groups (lane bits 4..5); each group's value counted once.
    rate += __shfl_xor(rate, 16, 64);
    rate += __shfl_xor(rate, 32, 64);

    if (lane == 0) ws[b] = rate;   // plain store, no contention
}

// One block reduces the 8192 per-batch rates and writes the scalar loss.
__global__ __launch_bounds__(1024) void reduce_kernel(
        const float* __restrict__ ws, float* __restrict__ out) {
    __shared__ float sPart[16];
    float s = 0.0f;
    #pragma unroll
    for (int i = 0; i < 8; ++i)
        s += ws[threadIdx.x + i * 1024];

    #pragma unroll
    for (int m = 1; m < 64; m <<= 1)
        s += __shfl_xor(s, m, 64);

    const int w = threadIdx.x >> 6;
    const int l = threadIdx.x & 63;
    if (l == 0) sPart[w] = s;
    __syncthreads();

    if (w == 0) {
        float t = (l < 16) ? sPart[l] : 0.0f;
        #pragma unroll
        for (int m = 1; m < 16; m <<= 1)
            t += __shfl_xor(t, m, 64);
        if (l == 0) out[0] = t * (-1.0f / 8192.0f);
    }
}

extern "C" void kernel_launch(void* const* d_in, const int* in_sizes, int n_in,
                              void* d_out, int out_size, void* d_ws, size_t ws_size,
                              hipStream_t stream) {
    const float* H = (const float*)d_in[0];
    const float* P = (const float*)d_in[1];
    float* out = (float*)d_out;
    float* ws  = (float*)d_ws;   // 8192 floats of per-batch rates

    // 8192 batches, 1 wave per batch, 4 waves (batches) per 256-thread block
    sumrate_kernel<<<8192 / 4, 256, 0, stream>>>(H, P, ws);
    reduce_kernel<<<1, 1024, 0, stream>>>(ws, out);
}

// Round 6
// 26.998 us; speedup vs baseline: 4.8275x; 1.0113x over previous
//
#include <hip/hip_runtime.h>

// Problem constants (match reference):
//   B = 8192 batches, N = 64 antennas, K = 16 users, NOISE = 1.0
//   H: [B, N, K, 2] f32  (re/im interleaved, 32 floats per n-row)
//   P: [B, 2*N*K]  f32  (first N*K = Pr[n][j], second N*K = Pi[n][j])
// Output: scalar f32 = -(1/B) * sum_{b,k} log2(1 + sig/interf)
//
// R6 (= R5 + register budget): R5's VGPR_Count=44 showed the compiler
// re-rolled the 48-load prologue to chase 8-waves/EU occupancy, exposing
// HBM latency repeatedly per wave. __launch_bounds__(256,4) gives a
// 128-VGPR budget: all 48 loads issue back-to-back (one vmcnt drain),
// occupancy still 4 waves/EU. Complex 16x16x64 matmul per batch via
// 8 x mfma_f32_16x16x32_bf16; fragments global-loaded directly
// (every byte exactly once, coalesced); f32->bf16 via v_cvt_pk_bf16_f32.
// No atomics. C/D layout col=lane&15, row=4*(lane>>4)+reg (m89-verified).

typedef short bf16x8 __attribute__((ext_vector_type(8)));
typedef float f32x4  __attribute__((ext_vector_type(4)));
typedef int   i32x4  __attribute__((ext_vector_type(4)));

__device__ __forceinline__ int pk2(float lo, float hi) {
    int r;
    asm("v_cvt_pk_bf16_f32 %0, %1, %2" : "=v"(r) : "v"(lo), "v"(hi));
    return r;   // bf16(lo) in low 16 bits, bf16(hi) in high 16 bits (RNE)
}

__device__ __forceinline__ bf16x8 mk8(const float* v) {  // v[8] -> packed bf16 frag
    i32x4 t;
    #pragma unroll
    for (int i = 0; i < 4; ++i) t[i] = pk2(v[2 * i], v[2 * i + 1]);
    return __builtin_bit_cast(bf16x8, t);
}

__device__ __forceinline__ bf16x8 negbf(bf16x8 a) {      // flip all 8 sign bits
    i32x4 t = __builtin_bit_cast(i32x4, a);
    #pragma unroll
    for (int i = 0; i < 4; ++i) t[i] ^= 0x80008000;
    return __builtin_bit_cast(bf16x8, t);
}

#define MFMA __builtin_amdgcn_mfma_f32_16x16x32_bf16

__global__ __launch_bounds__(256, 4) void sumrate_kernel(
        const float* __restrict__ H, const float* __restrict__ P,
        float* __restrict__ ws) {
    __shared__ float sRate[4];

    const int wave = threadIdx.x >> 6;        // 4 waves/block, 1 batch each
    const int lane = threadIdx.x & 63;
    const int b    = blockIdx.x * 4 + wave;
    const int j    = lane & 15;               // A row (k) and B col (j)
    const int g    = lane >> 4;               // n-slice group 0..3
    const int n0   = g * 8;                   // this lane's base n

    const float* Hb = H + (size_t)b * 2048;
    const float* Pb = P + (size_t)b * 2048;
    const float* hA = Hb + n0 * 32 + 2 * j;   // (re,im) of H[n][k], n-stride 32 f
    const float* pB = Pb + n0 * 16 + j;       // Pr[n][j], n-stride 16 f

    // ---- Global loads: every byte exactly once, coalesced, all in flight ----
    float2 h0[8], h1[8];                      // H halves (n 0..31 / 32..63)
    float pr0[8], pr1[8], pi0[8], pi1[8];     // P halves, re/im
    #pragma unroll
    for (int r = 0; r < 8; ++r) {
        h0[r] = *reinterpret_cast<const float2*>(hA + r * 32);
        h1[r] = *reinterpret_cast<const float2*>(hA + 1024 + r * 32);
        pr0[r] = pB[r * 16];
        pr1[r] = pB[512 + r * 16];
        pi0[r] = pB[1024 + r * 16];
        pi1[r] = pB[1536 + r * 16];
    }

    // ---- Pack bf16 fragments (A and B use the identical (lane,reg)->n map) ----
    float ar0[8], ai0[8], ar1[8], ai1[8];
    #pragma unroll
    for (int r = 0; r < 8; ++r) {
        ar0[r] = h0[r].x; ai0[r] = h0[r].y;
        ar1[r] = h1[r].x; ai1[r] = h1[r].y;
    }
    const bf16x8 Ahr0 = mk8(ar0), Ahr1 = mk8(ar1);
    const bf16x8 Ahi0 = mk8(ai0), Ahi1 = mk8(ai1);
    const bf16x8 Bpr0 = mk8(pr0), Bpr1 = mk8(pr1);
    const bf16x8 Bpi0 = mk8(pi0), Bpi1 = mk8(pi1);

    // ---- Complex 16x16x64 matmul: Dr = HrPr - HiPi, Di = HrPi + HiPr ----
    f32x4 dr = {0.f, 0.f, 0.f, 0.f}, di = {0.f, 0.f, 0.f, 0.f};
    dr = MFMA(Ahr0, Bpr0, dr, 0, 0, 0);
    dr = MFMA(Ahr1, Bpr1, dr, 0, 0, 0);
    dr = MFMA(negbf(Ahi0), Bpi0, dr, 0, 0, 0);
    dr = MFMA(negbf(Ahi1), Bpi1, dr, 0, 0, 0);
    di = MFMA(Ahr0, Bpi0, di, 0, 0, 0);
    di = MFMA(Ahr1, Bpi1, di, 0, 0, 0);
    di = MFMA(Ahi0, Bpr0, di, 0, 0, 0);
    di = MFMA(Ahi1, Bpr1, di, 0, 0, 0);

    // ---- Epilogue: C/D layout col=j=lane&15, row=k=4*g+reg ----
    float tot[4], sig[4];
    #pragma unroll
    for (int r = 0; r < 4; ++r) {
        const float mag = dr[r] * dr[r] + di[r] * di[r];
        const int k = g * 4 + r;
        tot[r] = mag;
        sig[r] = (j == k) ? mag : 0.0f;
    }
    // Row-sum over j: reduce across the 16 lanes of this g-group (low 4 bits).
    #pragma unroll
    for (int m = 1; m < 16; m <<= 1) {
        #pragma unroll
        for (int r = 0; r < 4; ++r) {
            tot[r] += __shfl_xor(tot[r], m, 64);
            sig[r] += __shfl_xor(sig[r], m, 64);
        }
    }
    // rate for this group's 4 k's (identical across the 16 lanes of the group)
    float rate = 0.0f;
    #pragma unroll
    for (int r = 0; r < 4; ++r)
        rate += log2f(1.0f + sig[r] / (tot[r] - sig[r] + 1.0f));
    // Sum the 4 groups (lane bits 4..5); each group's value counted once.
    rate += __shfl_xor(rate, 16, 64);
    rate += __shfl_xor(rate, 32, 64);

    // Combine the block's 4 per-batch rates -> one store per block.
    if (lane == 0) sRate[wave] = rate;
    __syncthreads();
    if (threadIdx.x == 0)
        ws[blockIdx.x] = sRate[0] + sRate[1] + sRate[2] + sRate[3];
}

// One block reduces the 2048 per-block rates and writes the scalar loss.
__global__ __launch_bounds__(1024) void reduce_kernel(
        const float* __restrict__ ws, float* __restrict__ out) {
    __shared__ float sPart[16];
    float s = ws[threadIdx.x] + ws[threadIdx.x + 1024];

    #pragma unroll
    for (int m = 1; m < 64; m <<= 1)
        s += __shfl_xor(s, m, 64);

    const int w = threadIdx.x >> 6;
    const int l = threadIdx.x & 63;
    if (l == 0) sPart[w] = s;
    __syncthreads();

    if (w == 0) {
        float t = (l < 16) ? sPart[l] : 0.0f;
        #pragma unroll
        for (int m = 1; m < 16; m <<= 1)
            t += __shfl_xor(t, m, 64);
        if (l == 0) out[0] = t * (-1.0f / 8192.0f);
    }
}

extern "C" void kernel_launch(void* const* d_in, const int* in_sizes, int n_in,
                              void* d_out, int out_size, void* d_ws, size_t ws_size,
                              hipStream_t stream) {
    const float* H = (const float*)d_in[0];
    const float* P = (const float*)d_in[1];
    float* out = (float*)d_out;
    float* ws  = (float*)d_ws;   // 2048 floats of per-block rate sums

    // 8192 batches, 1 wave per batch, 4 waves (batches) per 256-thread block
    sumrate_kernel<<<8192 / 4, 256, 0, stream>>>(H, P, ws);
    reduce_kernel<<<1, 1024, 0, stream>>>(ws, out);
}